// Round 1
// baseline (6647.842 us; speedup 1.0000x reference)
//
#include <hip/hip_runtime.h>
#include <math.h>

// ---------- helpers: monotonic float<->uint encoding for atomic max ----------
__device__ __forceinline__ unsigned fenc(float f) {
    unsigned u = __float_as_uint(f);
    return (u & 0x80000000u) ? ~u : (u | 0x80000000u);
}
__device__ __forceinline__ float fdec(unsigned u) {
    unsigned v = (u & 0x80000000u) ? (u ^ 0x80000000u) : ~u;
    return __uint_as_float(v);
}

// ---------- K1: q,k,v = node_features @ {Wq,Wk,Wv} ----------
__global__ __launch_bounds__(256) void qkv_kernel(
    const float* __restrict__ x,
    const float* __restrict__ Wq, const float* __restrict__ Wk, const float* __restrict__ Wv,
    float* __restrict__ q, float* __restrict__ k, float* __restrict__ v, int N)
{
    __shared__ float sW[3][64][64];
    __shared__ float sx[4][64];
    int t = threadIdx.x;
    for (int i = t; i < 4096; i += 256) {
        sW[0][i >> 6][i & 63] = Wq[i];
        sW[1][i >> 6][i & 63] = Wk[i];
        sW[2][i >> 6][i & 63] = Wv[i];
    }
    __syncthreads();
    int c = t & 63, sub = t >> 6;
    for (int base = blockIdx.x * 4; base < N; base += gridDim.x * 4) {
        int n = base + sub;
        if (n < N) sx[sub][c] = x[(size_t)n * 64 + c];
        __syncthreads();
        if (n < N) {
            float aq = 0.f, ak = 0.f, av = 0.f;
            #pragma unroll
            for (int i = 0; i < 64; i++) {
                float xv = sx[sub][i];
                aq += xv * sW[0][i][c];
                ak += xv * sW[1][i][c];
                av += xv * sW[2][i][c];
            }
            q[(size_t)n * 64 + c] = aq;
            k[(size_t)n * 64 + c] = ak;
            v[(size_t)n * 64 + c] = av;
        }
        __syncthreads();
    }
}

// ---------- K2: per-edge scores + segment max (atomic) ----------
// one wave (64 lanes) per edge; lane d computes ep[d] via readlane-broadcast matvec
__global__ __launch_bounds__(256) void score_kernel(
    const float* __restrict__ ef, const int* __restrict__ eidx,
    const float* __restrict__ q, const float* __restrict__ k,
    const float* __restrict__ We,
    float* __restrict__ scores, unsigned* __restrict__ smax, int E)
{
    __shared__ float sWe[64][64];
    int t = threadIdx.x;
    for (int i = t; i < 4096; i += 256) sWe[i >> 6][i & 63] = We[i];
    __syncthreads();
    int lane = t & 63, wid = t >> 6;
    for (long e = (long)blockIdx.x * 4 + wid; e < E; e += (long)gridDim.x * 4) {
        float efv = ef[e * 64 + lane];
        float epd = 0.f;
        #pragma unroll
        for (int i = 0; i < 64; i++) {
            float xv = __shfl(efv, i, 64);
            epd += xv * sWe[i][lane];
        }
        int src = eidx[e], tgt = eidx[E + e];
        float kk = k[(size_t)src * 64 + lane] + epd;
        float qq = q[(size_t)tgt * 64 + lane];
        float p = qq * kk;
        p += __shfl_xor(p, 8, 64);
        p += __shfl_xor(p, 4, 64);
        p += __shfl_xor(p, 2, 64);
        p += __shfl_xor(p, 1, 64);
        if ((lane & 15) == 0) {
            float s = p * 0.25f;           // / sqrt(16)
            int h = lane >> 4;
            scores[e * 4 + h] = s;
            atomicMax(&smax[(size_t)tgt * 4 + h], fenc(s));
        }
    }
}

// ---------- K3: ex = exp(score - smax[tgt]); denom = segment_sum(ex) ----------
__global__ __launch_bounds__(256) void ex_kernel(
    const int* __restrict__ eidx, const unsigned* __restrict__ smax,
    float* __restrict__ scores, float* __restrict__ denom, int E)
{
    long i = (long)blockIdx.x * blockDim.x + threadIdx.x;  // over E*4
    if (i < (long)E * 4) {
        long e = i >> 2;
        int h = (int)(i & 3);
        int tgt = eidx[E + e];
        float m = fdec(smax[(size_t)tgt * 4 + h]);
        float ex = expf(scores[i] - m);
        scores[i] = ex;                    // overwrite with ex
        atomicAdd(&denom[(size_t)tgt * 4 + h], ex);
    }
}

// ---------- K4: msg = alpha * (v[src] + ep); agg = segment_sum(msg) ----------
__global__ __launch_bounds__(256) void agg_kernel(
    const float* __restrict__ ef, const int* __restrict__ eidx,
    const float* __restrict__ v, const float* __restrict__ We,
    const float* __restrict__ exs, const float* __restrict__ denom,
    float* __restrict__ agg, int E)
{
    __shared__ float sWe[64][64];
    int t = threadIdx.x;
    for (int i = t; i < 4096; i += 256) sWe[i >> 6][i & 63] = We[i];
    __syncthreads();
    int lane = t & 63, wid = t >> 6;
    for (long e = (long)blockIdx.x * 4 + wid; e < E; e += (long)gridDim.x * 4) {
        float efv = ef[e * 64 + lane];
        float epd = 0.f;
        #pragma unroll
        for (int i = 0; i < 64; i++) {
            float xv = __shfl(efv, i, 64);
            epd += xv * sWe[i][lane];
        }
        int src = eidx[e], tgt = eidx[E + e];
        int h = lane >> 4;
        float alpha = exs[e * 4 + h] / (denom[(size_t)tgt * 4 + h] + 1e-9f);
        float msg = alpha * (v[(size_t)src * 64 + lane] + epd);
        atomicAdd(&agg[(size_t)tgt * 64 + lane], msg);
    }
}

// ---------- K5: new_nodes = node_features + agg @ Wo ----------
__global__ __launch_bounds__(256) void wo_kernel(
    const float* __restrict__ agg, const float* __restrict__ x,
    const float* __restrict__ Wo, float* __restrict__ out, int N)
{
    __shared__ float sW[64][64];
    __shared__ float sx[4][64];
    int t = threadIdx.x;
    for (int i = t; i < 4096; i += 256) sW[i >> 6][i & 63] = Wo[i];
    __syncthreads();
    int c = t & 63, sub = t >> 6;
    for (int base = blockIdx.x * 4; base < N; base += gridDim.x * 4) {
        int n = base + sub;
        if (n < N) sx[sub][c] = agg[(size_t)n * 64 + c];
        __syncthreads();
        if (n < N) {
            float acc = 0.f;
            #pragma unroll
            for (int i = 0; i < 64; i++) acc += sx[sub][i] * sW[i][c];
            out[(size_t)n * 64 + c] = x[(size_t)n * 64 + c] + acc;
        }
        __syncthreads();
    }
}

// ---------- K6: edge classifier: gelu(concat @ W1 + b1) @ W2 + b2 ----------
__global__ __launch_bounds__(256) void cls_kernel(
    const float* __restrict__ nn, const float* __restrict__ ef,
    const int* __restrict__ eidx,
    const float* __restrict__ W1, const float* __restrict__ b1,
    const float* __restrict__ W2, const float* __restrict__ b2,
    float* __restrict__ out, int E)
{
    __shared__ float sW1[192][64];
    __shared__ float sW2[128];
    __shared__ float sb1[64];
    __shared__ float sb2[2];
    int t = threadIdx.x;
    for (int i = t; i < 192 * 64; i += 256) sW1[i >> 6][i & 63] = W1[i];
    if (t < 128) sW2[t] = W2[t];
    if (t < 64) sb1[t] = b1[t];
    if (t < 2) sb2[t] = b2[t];
    __syncthreads();
    int lane = t & 63, wid = t >> 6;
    for (long e = (long)blockIdx.x * 4 + wid; e < E; e += (long)gridDim.x * 4) {
        int src = eidx[e], tgt = eidx[E + e];
        float a = nn[(size_t)src * 64 + lane];
        float b = nn[(size_t)tgt * 64 + lane];
        float c = ef[e * 64 + lane];
        float h = sb1[lane];
        #pragma unroll
        for (int i = 0; i < 64; i++) h += __shfl(a, i, 64) * sW1[i][lane];
        #pragma unroll
        for (int i = 0; i < 64; i++) h += __shfl(b, i, 64) * sW1[64 + i][lane];
        #pragma unroll
        for (int i = 0; i < 64; i++) h += __shfl(c, i, 64) * sW1[128 + i][lane];
        // exact GELU: x * 0.5 * (1 + erf(x/sqrt(2)))
        float g = 0.5f * h * (1.f + erff(h * 0.70710678118654752f));
        float p0 = g * sW2[lane * 2 + 0];
        float p1 = g * sW2[lane * 2 + 1];
        #pragma unroll
        for (int o = 32; o > 0; o >>= 1) {
            p0 += __shfl_xor(p0, o, 64);
            p1 += __shfl_xor(p1, o, 64);
        }
        if (lane == 0) {
            out[e * 2 + 0] = p0 + sb2[0];
            out[e * 2 + 1] = p1 + sb2[1];
        }
    }
}

extern "C" void kernel_launch(void* const* d_in, const int* in_sizes, int n_in,
                              void* d_out, int out_size, void* d_ws, size_t ws_size,
                              hipStream_t stream)
{
    const float* node = (const float*)d_in[0];
    const float* ef   = (const float*)d_in[1];
    const int*   eidx = (const int*)d_in[2];
    const float* Wq   = (const float*)d_in[3];
    const float* Wk   = (const float*)d_in[4];
    const float* Wv   = (const float*)d_in[5];
    const float* We   = (const float*)d_in[6];
    const float* Wo   = (const float*)d_in[7];
    const float* W1   = (const float*)d_in[8];
    const float* b1   = (const float*)d_in[9];
    const float* W2   = (const float*)d_in[10];
    const float* b2   = (const float*)d_in[11];
    float* out = (float*)d_out;

    int N = in_sizes[0] / 64;
    int E = in_sizes[1] / 64;

    // workspace layout (floats)
    float* q      = (float*)d_ws;
    float* k      = q + (size_t)N * 64;
    float* v      = k + (size_t)N * 64;
    float* newn   = v + (size_t)N * 64;
    float* scores = newn + (size_t)N * 64;              // E*4, later holds ex
    unsigned* smax = (unsigned*)(scores + (size_t)E * 4); // N*4 (encoded)
    float* denom  = (float*)(smax + (size_t)N * 4);     // N*4
    float* agg    = denom + (size_t)N * 4;              // N*64

    // zero smax(=enc -inf sentinel), denom, agg in one contiguous memset
    hipMemsetAsync(smax, 0, ((size_t)N * 4 + (size_t)N * 4 + (size_t)N * 64) * 4, stream);

    qkv_kernel<<<512, 256, 0, stream>>>(node, Wq, Wk, Wv, q, k, v, N);
    score_kernel<<<2048, 256, 0, stream>>>(ef, eidx, q, k, We, scores, smax, E);
    ex_kernel<<<(int)(((long)E * 4 + 255) / 256), 256, 0, stream>>>(eidx, smax, scores, denom, E);
    agg_kernel<<<2048, 256, 0, stream>>>(ef, eidx, v, We, scores, denom, agg, E);
    wo_kernel<<<512, 256, 0, stream>>>(agg, node, Wo, newn, N);
    cls_kernel<<<2048, 256, 0, stream>>>(newn, ef, eidx, W1, b1, W2, b2, out, E);
}

// Round 2
// 746.192 us; speedup vs baseline: 8.9090x; 8.9090x over previous
//
#include <hip/hip_runtime.h>
#include <math.h>

typedef __attribute__((ext_vector_type(8))) short bf16x8;
typedef __attribute__((ext_vector_type(4))) float f32x4;

// round-to-nearest-even float -> bf16 (as short)
__device__ __forceinline__ short f2bf(float f) {
    unsigned u = __float_as_uint(f);
    unsigned r = (u + 0x7FFFu + ((u >> 16) & 1u)) >> 16;
    return (short)r;
}

// XOR swizzle of a byte offset within a row (spreads 16B slots across 8 banks-groups)
__device__ __forceinline__ int swz(int row, int kbyte) {
    return kbyte ^ ((row & 7) << 4);
}

// ---------- K1: q,k,v = node_features @ {Wq,Wk,Wv} (VALU, small) ----------
__global__ __launch_bounds__(256) void qkv_kernel(
    const float* __restrict__ x,
    const float* __restrict__ Wq, const float* __restrict__ Wk, const float* __restrict__ Wv,
    float* __restrict__ q, float* __restrict__ k, float* __restrict__ v, int N)
{
    __shared__ float sW[3][64][64];
    __shared__ float sx[4][64];
    int t = threadIdx.x;
    for (int i = t; i < 4096; i += 256) {
        sW[0][i >> 6][i & 63] = Wq[i];
        sW[1][i >> 6][i & 63] = Wk[i];
        sW[2][i >> 6][i & 63] = Wv[i];
    }
    __syncthreads();
    int c = t & 63, sub = t >> 6;
    for (int base = blockIdx.x * 4; base < N; base += gridDim.x * 4) {
        int n = base + sub;
        if (n < N) sx[sub][c] = x[(size_t)n * 64 + c];
        __syncthreads();
        if (n < N) {
            float aq = 0.f, ak = 0.f, av = 0.f;
            #pragma unroll
            for (int i = 0; i < 64; i++) {
                float xv = sx[sub][i];
                aq += xv * sW[0][i][c];
                ak += xv * sW[1][i][c];
                av += xv * sW[2][i][c];
            }
            q[(size_t)n * 64 + c] = aq;
            k[(size_t)n * 64 + c] = ak;
            v[(size_t)n * 64 + c] = av;
        }
        __syncthreads();
    }
}

// ---- shared helper: stage 64x64 weight (transposed, bf16, swizzled rows of 128B) ----
__device__ __forceinline__ void stage_w64T(const float* __restrict__ W, short* sWT, int t) {
    for (int i = t; i < 4096; i += 256) {
        int k = i >> 6, n = i & 63;             // W[k][n], coalesced in n
        short vv = f2bf(W[i]);
        int kb = k * 2;
        int off = n * 128 + (swz(n, kb & ~15) | (kb & 15));
        *(short*)((char*)sWT + off) = vv;
    }
}

// ---- build ep (64 edges x 64) into ep_lds via MFMA; A gathered direct from ef ----
__device__ __forceinline__ void ep_mfma(
    const float* __restrict__ ef, const short* sWeT, float* ep_lds,
    size_t tile64, int t)
{
    int lane = t & 63, w = t >> 6;
    f32x4 acc[4];
    #pragma unroll
    for (int nt = 0; nt < 4; nt++) acc[nt] = (f32x4){0.f, 0.f, 0.f, 0.f};

    #pragma unroll
    for (int kk = 0; kk < 2; kk++) {
        const float* base = ef + (tile64 + (size_t)(w * 16 + (lane & 15))) * 64
                               + kk * 32 + (lane >> 4) * 8;
        float4 x0 = *(const float4*)(base);
        float4 x1 = *(const float4*)(base + 4);
        bf16x8 a;
        a[0] = f2bf(x0.x); a[1] = f2bf(x0.y); a[2] = f2bf(x0.z); a[3] = f2bf(x0.w);
        a[4] = f2bf(x1.x); a[5] = f2bf(x1.y); a[6] = f2bf(x1.z); a[7] = f2bf(x1.w);
        #pragma unroll
        for (int nt = 0; nt < 4; nt++) {
            int n = nt * 16 + (lane & 15);
            int kb = kk * 64 + (lane >> 4) * 16;
            bf16x8 b = *(const bf16x8*)((const char*)sWeT + n * 128 + swz(n, kb));
            acc[nt] = __builtin_amdgcn_mfma_f32_16x16x32_bf16(a, b, acc[nt], 0, 0, 0);
        }
    }
    #pragma unroll
    for (int nt = 0; nt < 4; nt++)
        #pragma unroll
        for (int r = 0; r < 4; r++) {
            int row = w * 16 + (lane >> 4) * 4 + r;
            int col = nt * 16 + (lane & 15);
            ep_lds[row * 66 + col] = acc[nt][r];
        }
}

// ---------- K2: ep + scores + exp + denom (atomicAdd) ----------
__global__ __launch_bounds__(256) void score_kernel(
    const float* __restrict__ ef, const int* __restrict__ eidx,
    const float* __restrict__ q, const float* __restrict__ k,
    const float* __restrict__ We,
    float* __restrict__ exs, float* __restrict__ denom, int E)
{
    __shared__ short sWeT[4096];
    __shared__ float ep_lds[64 * 66];
    __shared__ int sidx[64], tidx[64];
    int t = threadIdx.x;
    stage_w64T(We, sWeT, t);
    __syncthreads();

    int ntiles = E >> 6;
    for (int tile = blockIdx.x; tile < ntiles; tile += gridDim.x) {
        size_t tile64 = (size_t)tile * 64;
        if (t < 64) {
            sidx[t] = eidx[tile64 + t];
            tidx[t] = eidx[(size_t)E + tile64 + t];
        }
        __syncthreads();
        ep_mfma(ef, sWeT, ep_lds, tile64, t);
        __syncthreads();

        // thread = (edge e_loc = t>>2, head h = t&3)
        int e_loc = t >> 2, h = t & 3;
        int src = sidx[e_loc], tgt = tidx[e_loc];
        const float4* qp = (const float4*)(q + (size_t)tgt * 64 + h * 16);
        const float4* kp = (const float4*)(k + (size_t)src * 64 + h * 16);
        const float* epp = ep_lds + e_loc * 66 + h * 16;
        float s = 0.f;
        #pragma unroll
        for (int j = 0; j < 4; j++) {
            float4 qq = qp[j];
            float4 kk = kp[j];
            s += qq.x * (kk.x + epp[j * 4 + 0]);
            s += qq.y * (kk.y + epp[j * 4 + 1]);
            s += qq.z * (kk.z + epp[j * 4 + 2]);
            s += qq.w * (kk.w + epp[j * 4 + 3]);
        }
        float ex = __expf(s * 0.25f);
        exs[(tile64 + e_loc) * 4 + h] = ex;
        atomicAdd(&denom[(size_t)tgt * 4 + h], ex);
        __syncthreads();
    }
}

// ---------- K3: ep + msg + agg (atomicAdd) ----------
__global__ __launch_bounds__(256) void agg_kernel(
    const float* __restrict__ ef, const int* __restrict__ eidx,
    const float* __restrict__ v, const float* __restrict__ We,
    const float* __restrict__ exs, const float* __restrict__ denom,
    float* __restrict__ agg, int E)
{
    __shared__ short sWeT[4096];
    __shared__ float ep_lds[64 * 66];
    __shared__ int sidx[64], tidx[64];
    int t = threadIdx.x;
    stage_w64T(We, sWeT, t);
    __syncthreads();

    int lane = t & 63, w = t >> 6;
    int ntiles = E >> 6;
    for (int tile = blockIdx.x; tile < ntiles; tile += gridDim.x) {
        size_t tile64 = (size_t)tile * 64;
        if (t < 64) {
            sidx[t] = eidx[tile64 + t];
            tidx[t] = eidx[(size_t)E + tile64 + t];
        }
        __syncthreads();
        ep_mfma(ef, sWeT, ep_lds, tile64, t);
        __syncthreads();

        #pragma unroll 4
        for (int i = 0; i < 16; i++) {
            int e_loc = w * 16 + i;
            int src = sidx[e_loc], tgt = tidx[e_loc];
            float ex = exs[(tile64 + e_loc) * 4 + (lane >> 4)];
            float den = denom[(size_t)tgt * 4 + (lane >> 4)];
            float alpha = ex / (den + 1e-9f);
            float msg = alpha * (v[(size_t)src * 64 + lane] + ep_lds[e_loc * 66 + lane]);
            atomicAdd(&agg[(size_t)tgt * 64 + lane], msg);
        }
        __syncthreads();
    }
}

// ---------- K4: new_nodes = node_features + agg @ Wo ----------
__global__ __launch_bounds__(256) void wo_kernel(
    const float* __restrict__ agg, const float* __restrict__ x,
    const float* __restrict__ Wo, float* __restrict__ out, int N)
{
    __shared__ float sW[64][64];
    __shared__ float sx[4][64];
    int t = threadIdx.x;
    for (int i = t; i < 4096; i += 256) sW[i >> 6][i & 63] = Wo[i];
    __syncthreads();
    int c = t & 63, sub = t >> 6;
    for (int base = blockIdx.x * 4; base < N; base += gridDim.x * 4) {
        int n = base + sub;
        if (n < N) sx[sub][c] = agg[(size_t)n * 64 + c];
        __syncthreads();
        if (n < N) {
            float acc = 0.f;
            #pragma unroll
            for (int i = 0; i < 64; i++) acc += sx[sub][i] * sW[i][c];
            out[(size_t)n * 64 + c] = x[(size_t)n * 64 + c] + acc;
        }
        __syncthreads();
    }
}

// ---------- K5: classifier via MFMA: gelu([nn_src|nn_tgt|ef] @ W1 + b1) @ W2 + b2 ----------
__global__ __launch_bounds__(256) void cls_kernel(
    const float* __restrict__ nn, const float* __restrict__ ef,
    const int* __restrict__ eidx,
    const float* __restrict__ W1, const float* __restrict__ b1,
    const float* __restrict__ W2, const float* __restrict__ b2,
    float* __restrict__ out, int E)
{
    __shared__ short sWt1[64 * 192];        // [n][k] bf16, swizzled (384B rows)
    __shared__ float h_lds[64 * 66];
    __shared__ float sW2[128];
    __shared__ float sb1[64];
    __shared__ float sb2[2];
    __shared__ int sidx[64], tidx[64];
    int t = threadIdx.x;
    for (int i = t; i < 192 * 64; i += 256) {
        int k = i >> 6, n = i & 63;          // W1[k][n], coalesced in n
        short vv = f2bf(W1[i]);
        int kb = k * 2;
        int off = n * 384 + (swz(n, kb & ~15) | (kb & 15));
        *(short*)((char*)sWt1 + off) = vv;
    }
    if (t < 128) sW2[t] = W2[t];
    if (t < 64) sb1[t] = b1[t];
    if (t < 2) sb2[t] = b2[t];
    __syncthreads();

    int lane = t & 63, w = t >> 6;
    int ntiles = E >> 6;
    for (int tile = blockIdx.x; tile < ntiles; tile += gridDim.x) {
        size_t tile64 = (size_t)tile * 64;
        if (t < 64) {
            sidx[t] = eidx[tile64 + t];
            tidx[t] = eidx[(size_t)E + tile64 + t];
        }
        __syncthreads();

        f32x4 acc[4];
        #pragma unroll
        for (int nt = 0; nt < 4; nt++) acc[nt] = (f32x4){0.f, 0.f, 0.f, 0.f};

        int e16 = w * 16 + (lane & 15);      // this lane's edge row within the tile
        #pragma unroll
        for (int kk = 0; kk < 6; kk++) {
            const float* base;
            if (kk < 2)      base = nn + (size_t)sidx[e16] * 64 + kk * 32;
            else if (kk < 4) base = nn + (size_t)tidx[e16] * 64 + (kk - 2) * 32;
            else             base = ef + (tile64 + (size_t)e16) * 64 + (kk - 4) * 32;
            const float4* p = (const float4*)(base + (lane >> 4) * 8);
            float4 x0 = p[0], x1 = p[1];
            bf16x8 a;
            a[0] = f2bf(x0.x); a[1] = f2bf(x0.y); a[2] = f2bf(x0.z); a[3] = f2bf(x0.w);
            a[4] = f2bf(x1.x); a[5] = f2bf(x1.y); a[6] = f2bf(x1.z); a[7] = f2bf(x1.w);
            #pragma unroll
            for (int nt = 0; nt < 4; nt++) {
                int n = nt * 16 + (lane & 15);
                int kb = kk * 64 + (lane >> 4) * 16;
                bf16x8 b = *(const bf16x8*)((const char*)sWt1 + n * 384 + swz(n, kb));
                acc[nt] = __builtin_amdgcn_mfma_f32_16x16x32_bf16(a, b, acc[nt], 0, 0, 0);
            }
        }

        // bias + exact GELU, park in LDS
        #pragma unroll
        for (int nt = 0; nt < 4; nt++)
            #pragma unroll
            for (int r = 0; r < 4; r++) {
                int row = w * 16 + (lane >> 4) * 4 + r;
                int col = nt * 16 + (lane & 15);
                float h = acc[nt][r] + sb1[col];
                float g = 0.5f * h * (1.f + erff(h * 0.70710678118654752f));
                h_lds[row * 66 + col] = g;
            }
        __syncthreads();

        // second layer: [64,64] @ [64,2]
        if (t < 128) {
            int e = t >> 1, o = t & 1;
            float acc2 = sb2[o];
            const float* hr = h_lds + e * 66;
            #pragma unroll
            for (int j = 0; j < 64; j++) acc2 += hr[j] * sW2[j * 2 + o];
            out[(tile64 + (size_t)e) * 2 + o] = acc2;
        }
        __syncthreads();
    }
}

extern "C" void kernel_launch(void* const* d_in, const int* in_sizes, int n_in,
                              void* d_out, int out_size, void* d_ws, size_t ws_size,
                              hipStream_t stream)
{
    const float* node = (const float*)d_in[0];
    const float* ef   = (const float*)d_in[1];
    const int*   eidx = (const int*)d_in[2];
    const float* Wq   = (const float*)d_in[3];
    const float* Wk   = (const float*)d_in[4];
    const float* Wv   = (const float*)d_in[5];
    const float* We   = (const float*)d_in[6];
    const float* Wo   = (const float*)d_in[7];
    const float* W1   = (const float*)d_in[8];
    const float* b1   = (const float*)d_in[9];
    const float* W2   = (const float*)d_in[10];
    const float* b2   = (const float*)d_in[11];
    float* out = (float*)d_out;

    int N = in_sizes[0] / 64;
    int E = in_sizes[1] / 64;
    size_t N64 = (size_t)N * 64;

    float* q     = (float*)d_ws;
    float* k     = q + N64;
    float* v     = k + N64;
    float* newn  = v + N64;
    float* agg   = newn + N64;                 // N*64, zeroed
    float* denom = agg + N64;                  // N*4, zeroed
    float* exs   = denom + (size_t)N * 4;      // E*4

    hipMemsetAsync(agg, 0, (N64 + (size_t)N * 4) * sizeof(float), stream);

    qkv_kernel<<<512, 256, 0, stream>>>(node, Wq, Wk, Wv, q, k, v, N);
    score_kernel<<<2048, 256, 0, stream>>>(ef, eidx, q, k, We, exs, denom, E);
    agg_kernel<<<2048, 256, 0, stream>>>(ef, eidx, v, We, exs, denom, agg, E);
    wo_kernel<<<512, 256, 0, stream>>>(agg, node, Wo, newn, N);
    cls_kernel<<<2048, 256, 0, stream>>>(newn, ef, eidx, W1, b1, W2, b2, out, E);
}

// Round 3
// 674.004 us; speedup vs baseline: 9.8632x; 1.1071x over previous
//
#include <hip/hip_runtime.h>
#include <math.h>

typedef __attribute__((ext_vector_type(8))) short bf16x8;
typedef __attribute__((ext_vector_type(4))) float f32x4;

// round-to-nearest-even float -> bf16 (as short)
__device__ __forceinline__ short f2bf(float f) {
    unsigned u = __float_as_uint(f);
    unsigned r = (u + 0x7FFFu + ((u >> 16) & 1u)) >> 16;
    return (short)r;
}

// XOR swizzle of a byte offset within a row (spreads 16B slots across 8 bank-groups)
__device__ __forceinline__ int swz(int row, int kbyte) {
    return kbyte ^ ((row & 7) << 4);
}

// ---------- K1: q,k,v = node_features @ {Wq,Wk,Wv} ----------
__global__ __launch_bounds__(256) void qkv_kernel(
    const float* __restrict__ x,
    const float* __restrict__ Wq, const float* __restrict__ Wk, const float* __restrict__ Wv,
    float* __restrict__ q, float* __restrict__ k, float* __restrict__ v, int N)
{
    __shared__ float sW[3][64][64];
    __shared__ float sx[4][64];
    int t = threadIdx.x;
    for (int i = t; i < 4096; i += 256) {
        sW[0][i >> 6][i & 63] = Wq[i];
        sW[1][i >> 6][i & 63] = Wk[i];
        sW[2][i >> 6][i & 63] = Wv[i];
    }
    __syncthreads();
    int c = t & 63, sub = t >> 6;
    for (int base = blockIdx.x * 4; base < N; base += gridDim.x * 4) {
        int n = base + sub;
        if (n < N) sx[sub][c] = x[(size_t)n * 64 + c];
        __syncthreads();
        if (n < N) {
            float aq = 0.f, ak = 0.f, av = 0.f;
            #pragma unroll
            for (int i = 0; i < 64; i++) {
                float xv = sx[sub][i];
                aq += xv * sW[0][i][c];
                ak += xv * sW[1][i][c];
                av += xv * sW[2][i][c];
            }
            q[(size_t)n * 64 + c] = aq;
            k[(size_t)n * 64 + c] = ak;
            v[(size_t)n * 64 + c] = av;
        }
        __syncthreads();
    }
}

// ---- stage 64x64 weight (transposed, bf16, swizzled rows of 128B) ----
__device__ __forceinline__ void stage_w64T(const float* __restrict__ W, short* sWT, int t) {
    for (int i = t; i < 4096; i += 256) {
        int k = i >> 6, n = i & 63;             // W[k][n], coalesced in n
        short vv = f2bf(W[i]);
        int kb = k * 2;
        int off = n * 128 + (swz(n, kb & ~15) | (kb & 15));
        *(short*)((char*)sWT + off) = vv;
    }
}

// ---- build ep (64 edges x 64) into ep_lds via MFMA; A gathered direct from ef ----
__device__ __forceinline__ void ep_mfma(
    const float* __restrict__ ef, const short* sWeT, float* ep_lds,
    size_t tile64, int t)
{
    int lane = t & 63, w = t >> 6;
    f32x4 acc[4];
    #pragma unroll
    for (int nt = 0; nt < 4; nt++) acc[nt] = (f32x4){0.f, 0.f, 0.f, 0.f};

    #pragma unroll
    for (int kk = 0; kk < 2; kk++) {
        const float* base = ef + (tile64 + (size_t)(w * 16 + (lane & 15))) * 64
                               + kk * 32 + (lane >> 4) * 8;
        float4 x0 = *(const float4*)(base);
        float4 x1 = *(const float4*)(base + 4);
        bf16x8 a;
        a[0] = f2bf(x0.x); a[1] = f2bf(x0.y); a[2] = f2bf(x0.z); a[3] = f2bf(x0.w);
        a[4] = f2bf(x1.x); a[5] = f2bf(x1.y); a[6] = f2bf(x1.z); a[7] = f2bf(x1.w);
        #pragma unroll
        for (int nt = 0; nt < 4; nt++) {
            int n = nt * 16 + (lane & 15);
            int kb = kk * 64 + (lane >> 4) * 16;
            bf16x8 b = *(const bf16x8*)((const char*)sWeT + n * 128 + swz(n, kb));
            acc[nt] = __builtin_amdgcn_mfma_f32_16x16x32_bf16(a, b, acc[nt], 0, 0, 0);
        }
    }
    #pragma unroll
    for (int nt = 0; nt < 4; nt++)
        #pragma unroll
        for (int r = 0; r < 4; r++) {
            int row = w * 16 + (lane >> 4) * 4 + r;
            int col = nt * 16 + (lane & 15);
            ep_lds[row * 66 + col] = acc[nt][r];
        }
}

// ---------- K2: fused edge pass: ep + score + exp + denom atomic + UNNORMALIZED agg atomic ----------
__global__ __launch_bounds__(256) void edge_kernel(
    const float* __restrict__ ef, const int* __restrict__ eidx,
    const float* __restrict__ q, const float* __restrict__ k,
    const float* __restrict__ v, const float* __restrict__ We,
    float* __restrict__ denom, float* __restrict__ agg, int E)
{
    __shared__ short sWeT[4096];
    __shared__ float ep_lds[64 * 66];
    __shared__ float ex_lds[64 * 4];
    __shared__ int sidx[64], tidx[64];
    int t = threadIdx.x;
    stage_w64T(We, sWeT, t);
    __syncthreads();

    int lane = t & 63, w = t >> 6;
    int ntiles = E >> 6;
    for (int tile = blockIdx.x; tile < ntiles; tile += gridDim.x) {
        size_t tile64 = (size_t)tile * 64;
        if (t < 64) {
            sidx[t] = eidx[tile64 + t];
            tidx[t] = eidx[(size_t)E + tile64 + t];
        }
        __syncthreads();
        ep_mfma(ef, sWeT, ep_lds, tile64, t);
        __syncthreads();

        // phase B: thread = (edge e_loc = t>>2, head h = t&3): score, ex, denom atomic
        {
            int e_loc = t >> 2, h = t & 3;
            int src = sidx[e_loc], tgt = tidx[e_loc];
            const float4* qp = (const float4*)(q + (size_t)tgt * 64 + h * 16);
            const float4* kp = (const float4*)(k + (size_t)src * 64 + h * 16);
            const float* epp = ep_lds + e_loc * 66 + h * 16;
            float s = 0.f;
            #pragma unroll
            for (int j = 0; j < 4; j++) {
                float4 qq = qp[j];
                float4 kk = kp[j];
                s += qq.x * (kk.x + epp[j * 4 + 0]);
                s += qq.y * (kk.y + epp[j * 4 + 1]);
                s += qq.z * (kk.z + epp[j * 4 + 2]);
                s += qq.w * (kk.w + epp[j * 4 + 3]);
            }
            float ex = __expf(s * 0.25f);
            ex_lds[e_loc * 4 + h] = ex;
            atomicAdd(&denom[(size_t)tgt * 4 + h], ex);
        }
        __syncthreads();

        // phase C: wave w handles edges w*16+i; unnormalized message aggregation
        #pragma unroll 4
        for (int i = 0; i < 16; i++) {
            int e_loc = w * 16 + i;
            int src = sidx[e_loc], tgt = tidx[e_loc];
            float ex = ex_lds[e_loc * 4 + (lane >> 4)];
            float msg = ex * (v[(size_t)src * 64 + lane] + ep_lds[e_loc * 66 + lane]);
            atomicAdd(&agg[(size_t)tgt * 64 + lane], msg);
        }
        __syncthreads();
    }
}

// ---------- K3: new_nodes = node_features + (agg_un/denom) @ Wo ----------
__global__ __launch_bounds__(256) void wo_kernel(
    const float* __restrict__ agg, const float* __restrict__ denom,
    const float* __restrict__ x,
    const float* __restrict__ Wo, float* __restrict__ out, int N)
{
    __shared__ float sW[64][64];
    __shared__ float sx[4][64];
    int t = threadIdx.x;
    for (int i = t; i < 4096; i += 256) sW[i >> 6][i & 63] = Wo[i];
    __syncthreads();
    int c = t & 63, sub = t >> 6;
    for (int base = blockIdx.x * 4; base < N; base += gridDim.x * 4) {
        int n = base + sub;
        if (n < N) {
            float d = denom[(size_t)n * 4 + (c >> 4)] + 1e-9f;
            sx[sub][c] = agg[(size_t)n * 64 + c] / d;
        }
        __syncthreads();
        if (n < N) {
            float acc = 0.f;
            #pragma unroll
            for (int i = 0; i < 64; i++) acc += sx[sub][i] * sW[i][c];
            out[(size_t)n * 64 + c] = x[(size_t)n * 64 + c] + acc;
        }
        __syncthreads();
    }
}

// ---------- K4: classifier via MFMA; second layer fully in registers ----------
__global__ __launch_bounds__(256, 4) void cls_kernel(
    const float* __restrict__ nn, const float* __restrict__ ef,
    const int* __restrict__ eidx,
    const float* __restrict__ W1, const float* __restrict__ b1,
    const float* __restrict__ W2, const float* __restrict__ b2,
    float* __restrict__ out, int E)
{
    __shared__ short sWt1[64 * 192];        // [n][k] bf16, swizzled (384B rows)
    __shared__ float sW2[128];
    __shared__ float sb1[64];
    __shared__ float sb2[2];
    __shared__ int sidx[64], tidx[64];
    int t = threadIdx.x;
    for (int i = t; i < 192 * 64; i += 256) {
        int k = i >> 6, n = i & 63;          // W1[k][n], coalesced in n
        short vv = f2bf(W1[i]);
        int kb = k * 2;
        int off = n * 384 + (swz(n, kb & ~15) | (kb & 15));
        *(short*)((char*)sWt1 + off) = vv;
    }
    if (t < 128) sW2[t] = W2[t];
    if (t < 64) sb1[t] = b1[t];
    if (t < 2) sb2[t] = b2[t];
    __syncthreads();

    int lane = t & 63, w = t >> 6;
    int ntiles = E >> 6;
    for (int tile = blockIdx.x; tile < ntiles; tile += gridDim.x) {
        size_t tile64 = (size_t)tile * 64;
        if (t < 64) {
            sidx[t] = eidx[tile64 + t];
            tidx[t] = eidx[(size_t)E + tile64 + t];
        }
        __syncthreads();

        f32x4 acc[4];
        #pragma unroll
        for (int nt = 0; nt < 4; nt++) acc[nt] = (f32x4){0.f, 0.f, 0.f, 0.f};

        int e16 = w * 16 + (lane & 15);      // this lane's edge row within the tile
        #pragma unroll
        for (int kk = 0; kk < 6; kk++) {
            const float* base;
            if (kk < 2)      base = nn + (size_t)sidx[e16] * 64 + kk * 32;
            else if (kk < 4) base = nn + (size_t)tidx[e16] * 64 + (kk - 2) * 32;
            else             base = ef + (tile64 + (size_t)e16) * 64 + (kk - 4) * 32;
            const float4* p = (const float4*)(base + (lane >> 4) * 8);
            float4 x0 = p[0], x1 = p[1];
            bf16x8 a;
            a[0] = f2bf(x0.x); a[1] = f2bf(x0.y); a[2] = f2bf(x0.z); a[3] = f2bf(x0.w);
            a[4] = f2bf(x1.x); a[5] = f2bf(x1.y); a[6] = f2bf(x1.z); a[7] = f2bf(x1.w);
            #pragma unroll
            for (int nt = 0; nt < 4; nt++) {
                int n = nt * 16 + (lane & 15);
                int kb = kk * 64 + (lane >> 4) * 16;
                bf16x8 b = *(const bf16x8*)((const char*)sWt1 + n * 384 + swz(n, kb));
                acc[nt] = __builtin_amdgcn_mfma_f32_16x16x32_bf16(a, b, acc[nt], 0, 0, 0);
            }
        }

        // bias + exact GELU + second layer [64,64]@[64,2] via in-register shfl reduce.
        // acc[nt][r] is h for row = w*16+(lane>>4)*4+r, col = nt*16+(lane&15)
        #pragma unroll
        for (int r = 0; r < 4; r++) {
            float p0 = 0.f, p1 = 0.f;
            #pragma unroll
            for (int nt = 0; nt < 4; nt++) {
                int col = nt * 16 + (lane & 15);
                float h = acc[nt][r] + sb1[col];
                float g = 0.5f * h * (1.f + erff(h * 0.70710678118654752f));
                p0 += g * sW2[col * 2 + 0];
                p1 += g * sW2[col * 2 + 1];
            }
            #pragma unroll
            for (int o = 1; o < 16; o <<= 1) {
                p0 += __shfl_xor(p0, o, 64);
                p1 += __shfl_xor(p1, o, 64);
            }
            if ((lane & 15) == 0) {
                int row = w * 16 + (lane >> 4) * 4 + r;
                out[(tile64 + (size_t)row) * 2 + 0] = p0 + sb2[0];
                out[(tile64 + (size_t)row) * 2 + 1] = p1 + sb2[1];
            }
        }
        __syncthreads();
    }
}

extern "C" void kernel_launch(void* const* d_in, const int* in_sizes, int n_in,
                              void* d_out, int out_size, void* d_ws, size_t ws_size,
                              hipStream_t stream)
{
    const float* node = (const float*)d_in[0];
    const float* ef   = (const float*)d_in[1];
    const int*   eidx = (const int*)d_in[2];
    const float* Wq   = (const float*)d_in[3];
    const float* Wk   = (const float*)d_in[4];
    const float* Wv   = (const float*)d_in[5];
    const float* We   = (const float*)d_in[6];
    const float* Wo   = (const float*)d_in[7];
    const float* W1   = (const float*)d_in[8];
    const float* b1   = (const float*)d_in[9];
    const float* W2   = (const float*)d_in[10];
    const float* b2   = (const float*)d_in[11];
    float* out = (float*)d_out;

    int N = in_sizes[0] / 64;
    int E = in_sizes[1] / 64;
    size_t N64 = (size_t)N * 64;

    float* q     = (float*)d_ws;
    float* k     = q + N64;
    float* v     = k + N64;
    float* newn  = v + N64;
    float* agg   = newn + N64;                 // N*64 unnormalized, zeroed
    float* denom = agg + N64;                  // N*4, zeroed

    hipMemsetAsync(agg, 0, (N64 + (size_t)N * 4) * sizeof(float), stream);

    qkv_kernel<<<512, 256, 0, stream>>>(node, Wq, Wk, Wv, q, k, v, N);
    edge_kernel<<<2048, 256, 0, stream>>>(ef, eidx, q, k, v, We, denom, agg, E);
    wo_kernel<<<512, 256, 0, stream>>>(agg, denom, node, Wo, newn, N);
    cls_kernel<<<2048, 256, 0, stream>>>(newn, ef, eidx, W1, b1, W2, b2, out, E);
}